// Round 18
// baseline (29.124 us; speedup 1.0000x reference)
//
#include <hip/hip_runtime.h>

// DivEncLayer via MFMA — PRODUCER/CONSUMER WAVE SPECIALIZATION.
// Per (b,q): h = elu(x[b,q*8:+8]@W1[q] + b1[q]); LN(h); out = h@W2[q]+b2[q].
// B=16384, Q=128, S=8, U=32.
//
// r16/r17 post-mortem: phase costs are ADDITIVE (staging 9.8 + MFMA 3.3 +
// ELU/reduce 6.5 + epilogue 4.8 + setup); register-pipelining the staging
// into the compute waves' issue stream (r17) recovered only 1us. Fix: a
// DEDICATED producer wave owns all global x traffic (loads+cvt+ds_write,
// 2 panels ahead, 3-deep ring); 4 consumer waves (one q each) have zero
// staging instructions and never wait vmcnt. Barrier = lgkmcnt(0)+s_barrier
// (no vmcnt drain, r17-proven): producer's in-flight loads cross barriers.
// Ring safety: slot (it+1)%3 written in iter it was last read in iter it-2.
//
// v_mfma_f32_32x32x16_bf16 mapping (validated r2-r11):
//   A: lane l, reg j -> A[l&31][j + 8*(l>>5)]
//   B: lane l, reg j -> B[j + 8*(l>>5)][l&31]
//   D: lane l, reg r -> row u=(r&3)+8*(r>>2)+4*(l>>5), col b=l&31
// Packed A-frag: lanes<32 = bf16(W1^T) (k<8), lanes>=32 = bf16(W1-hi) (k>=8).
// B-frag: staged bf16 panel row u (halves dup) -> one ds_read_b128.
// D = (whi+wlo)*xhi + b1 (C-in fp32). LN+Dense2 folded:
//   out = rsqrt(var+eps)*(dot(e,g2) - mu*G) + C.
// Block = 5 waves (320 thr): w0-3 consumers (q=qt*4+w), w4 producer.
// 8 iters x 64 rows = 512-row band; grid (32,32) = 1024 blocks.
// lout gather -> float4 stores (write-exact, proven).

typedef __attribute__((ext_vector_type(8))) short short8;    // 8 bf16
typedef __attribute__((ext_vector_type(16))) float f32x16;

#define XS_STRIDE 40   // shorts per staged row (80 B): b128-aligned, 0-conflict (r11)

__device__ __forceinline__ short fbits(__bf16 b) { return __builtin_bit_cast(short, b); }

__device__ __forceinline__ float elu1(float v) {
    return v > 0.f ? v : __expf(v) - 1.f;
}

__device__ __forceinline__ short4 cvt4(float4 v) {
    short4 r;
    r.x = fbits((__bf16)v.x); r.y = fbits((__bf16)v.y);
    r.z = fbits((__bf16)v.z); r.w = fbits((__bf16)v.w);
    return r;
}

// barrier WITHOUT vmcnt drain: DS visibility only; global loads stay in flight
__device__ __forceinline__ void barrier_ds_only() {
    asm volatile("s_waitcnt lgkmcnt(0)" ::: "memory");
    __builtin_amdgcn_s_barrier();
}

__global__ __launch_bounds__(320, 4) void divenc_ws(
    const float* __restrict__ x,      // (16384, 1024)
    const float* __restrict__ W1,     // (128, 8, 32)
    const float* __restrict__ b1,     // (128, 32)
    const float* __restrict__ gamma,  // (128, 32)
    const float* __restrict__ beta,   // (128, 32)
    const float* __restrict__ W2,     // (128, 32)
    const float* __restrict__ b2,     // (128,)
    float* __restrict__ out)          // (16384, 128)
{
    __shared__ short xs[3][64 * XS_STRIDE];   // 3-deep panel ring (5 KB each)
    __shared__ float lout[512 * 5];           // results, padded stride 5 (10 KB)

    const int tid  = threadIdx.x;
    const int w    = tid >> 6;        // 0..3 consumers, 4 producer
    const int ln   = tid & 63;
    const int u    = ln & 31;
    const int half = ln >> 5;
    const int qt   = blockIdx.y;      // 0..31
    const int bx   = blockIdx.x;      // 0..31; band = rows bx*512..+511
    const int band = bx * 512;

    if (w == 4) {
        // ================= PRODUCER WAVE =================
        // per wave-load j: lane covers row j*8 + (ln>>3), 16B chunk (ln&7)
        const int prow = ln >> 3;
        const int chk  = ln & 7;
        const float* xg = x + qt * 32 + chk * 4;

        float4 A[8], Bv[8];
        #pragma unroll
        for (int j = 0; j < 8; ++j)
            A[j] = *(const float4*)(xg + (size_t)(band + j * 8 + prow) * 1024);
        #pragma unroll
        for (int j = 0; j < 8; ++j)
            Bv[j] = *(const float4*)(xg + (size_t)(band + 64 + j * 8 + prow) * 1024);
        // write panel 0 (compiler waits only A's loads: vmcnt(8))
        #pragma unroll
        for (int j = 0; j < 8; ++j)
            *(short4*)&xs[0][(j * 8 + prow) * XS_STRIDE + chk * 4] = cvt4(A[j]);
        barrier_ds_only();   // barrier #0: panel 0 ready

        #pragma unroll 1
        for (int it = 0; it < 8; ++it) {
            // issue loads for panel it+2 (clamped; discarded past the end)
            const int pn = (it + 2 > 7) ? 7 : (it + 2);
            float4 N[8];
            #pragma unroll
            for (int j = 0; j < 8; ++j)
                N[j] = *(const float4*)(xg + (size_t)(band + pn * 64 + j * 8 + prow) * 1024);
            // write panel it+1 from Bv (loaded one iter ago; latency covered)
            if (it < 7) {
                short* dst = &xs[(it + 1) % 3][0];
                #pragma unroll
                for (int j = 0; j < 8; ++j)
                    *(short4*)&dst[(j * 8 + prow) * XS_STRIDE + chk * 4] = cvt4(Bv[j]);
            }
            barrier_ds_only();   // barrier #it+1
            #pragma unroll
            for (int j = 0; j < 8; ++j) Bv[j] = N[j];   // rotate (producer is idle-rich)
        }
    } else {
        // ================= CONSUMER WAVES (one q each) =================
        const int q = qt * 4 + w;

        // A-frag: lanes<32 = whi (k=0..7), lanes>=32 = wlo (k=8..15)
        short8 wfrag;
        #pragma unroll
        for (int j = 0; j < 8; ++j) {
            float f  = W1[q * 256 + j * 32 + u];
            __bf16 h = (__bf16)f;
            wfrag[j] = half ? fbits((__bf16)(f - (float)h)) : fbits(h);
        }

        // params: biasr (MFMA C-in) + g2r in regs, vector loads
        f32x16 biasr, g2r;
        float G, C;
        {
            float gs = 0.f, cs = 0.f;
            #pragma unroll
            for (int c = 0; c < 4; ++c) {
                const int ub = q * 32 + 4 * half + 8 * c;
                float4 b1v = *(const float4*)&b1[ub];
                float4 gav = *(const float4*)&gamma[ub];
                float4 w2v = *(const float4*)&W2[ub];
                float4 bev = *(const float4*)&beta[ub];
                #pragma unroll
                for (int j = 0; j < 4; ++j) {
                    float g2 = ((const float*)&gav)[j] * ((const float*)&w2v)[j];
                    biasr[4 * c + j] = ((const float*)&b1v)[j];
                    g2r[4 * c + j]   = g2;
                    gs += g2;
                    cs += ((const float*)&bev)[j] * ((const float*)&w2v)[j];
                }
            }
            gs += __shfl_xor(gs, 32);   // halves hold complementary u-sets
            cs += __shfl_xor(cs, 32);
            G = gs;
            C = cs + b2[q];
        }

        barrier_ds_only();   // barrier #0: panel 0 ready

        #pragma unroll 1
        for (int it = 0; it < 8; ++it) {
            const int cur = it % 3;
            const int b0  = it * 64;

            short8 xa = *(const short8*)&xs[cur][u * XS_STRIDE + w * 8];
            short8 xb = *(const short8*)&xs[cur][(u + 32) * XS_STRIDE + w * 8];

            f32x16 accA = __builtin_amdgcn_mfma_f32_32x32x16_bf16(wfrag, xa, biasr, 0, 0, 0);
            f32x16 accB = __builtin_amdgcn_mfma_f32_32x32x16_bf16(wfrag, xb, biasr, 0, 0, 0);

            {
                float sum = 0.f, ss = 0.f, dot = 0.f;
                #pragma unroll
                for (int r = 0; r < 16; ++r) {
                    float e = elu1(accA[r]);
                    sum += e;
                    ss  = fmaf(e, e, ss);
                    dot = fmaf(e, g2r[r], dot);
                }
                sum += __shfl_xor(sum, 32);
                ss  += __shfl_xor(ss, 32);
                dot += __shfl_xor(dot, 32);
                float mu  = sum * 0.03125f;
                float var = fmaf(-mu, mu, ss * 0.03125f);
                float inv = rsqrtf(var + 1e-3f);
                float res = fmaf(inv, fmaf(-mu, G, dot), C);
                if (half == 0) lout[(b0 + u) * 5 + w] = res;
            }
            {
                float sum = 0.f, ss = 0.f, dot = 0.f;
                #pragma unroll
                for (int r = 0; r < 16; ++r) {
                    float e = elu1(accB[r]);
                    sum += e;
                    ss  = fmaf(e, e, ss);
                    dot = fmaf(e, g2r[r], dot);
                }
                sum += __shfl_xor(sum, 32);
                ss  += __shfl_xor(ss, 32);
                dot += __shfl_xor(dot, 32);
                float mu  = sum * 0.03125f;
                float var = fmaf(-mu, mu, ss * 0.03125f);
                float inv = rsqrtf(var + 1e-3f);
                float res = fmaf(inv, fmaf(-mu, G, dot), C);
                if (half == 0) lout[(b0 + 32 + u) * 5 + w] = res;
            }

            barrier_ds_only();   // reads of panel it done; panel it+1 ready
        }
    }

    __syncthreads();   // full drain before the gather

    // ---- gather/store: 512 rows, 2 per thread (first 4 waves), float4 each ----
    if (tid < 256) {
        const int r0 = tid;
        const int r1 = tid + 256;
        float4 o0, o1;
        o0.x = lout[r0 * 5 + 0]; o0.y = lout[r0 * 5 + 1];
        o0.z = lout[r0 * 5 + 2]; o0.w = lout[r0 * 5 + 3];
        o1.x = lout[r1 * 5 + 0]; o1.y = lout[r1 * 5 + 1];
        o1.z = lout[r1 * 5 + 2]; o1.w = lout[r1 * 5 + 3];
        *(float4*)(out + (size_t)(band + r0) * 128 + qt * 4) = o0;
        *(float4*)(out + (size_t)(band + r1) * 128 + qt * 4) = o1;
    }
}

extern "C" void kernel_launch(void* const* d_in, const int* in_sizes, int n_in,
                              void* d_out, int out_size, void* d_ws, size_t ws_size,
                              hipStream_t stream) {
    const float* x     = (const float*)d_in[0];
    const float* W1    = (const float*)d_in[1];
    const float* b1    = (const float*)d_in[2];
    const float* gamma = (const float*)d_in[3];
    const float* beta  = (const float*)d_in[4];
    const float* W2    = (const float*)d_in[5];
    const float* b2    = (const float*)d_in[6];
    float* out = (float*)d_out;

    dim3 grid(32, 32);   // (512-row bands, q-tiles of 4)
    divenc_ws<<<grid, 320, 0, stream>>>(x, W1, b1, gamma, beta, W2, b2, out);
}

// Round 19
// 28.944 us; speedup vs baseline: 1.0062x; 1.0062x over previous
//
#include <hip/hip_runtime.h>

// DivEncLayer via MFMA — r17 staging pipeline + DEFERRED EPILOGUE + packed-f32.
// Per (b,q): h = elu(x[b,q*8:+8]@W1[q] + b1[q]); LN(h); out = h@W2[q]+b2[q].
// B=16384, Q=128, S=8, U=32.
//
// r17/r18 post-mortem: staging overlap is NOT the lever (two nulls). r16
// marginals say the in-loop VALU/serial tail is: ELU+reduce 6.5us +
// shfl/epilogue 4.8us. This round removes the tail from the loop:
//  1) lanes write 3 PARTIALS per tile to LDS planes [metric][half][q][row]
//     (consecutive rows = consecutive banks, conflict-free; halves 2-way=free)
//     -> no shfl_xor, no epilogue, no branch in the loop.
//  2) batched gather: 4 epilogues/thread after one final barrier, then the
//     proven float4-per-row store.
//  3) packed f32: ELU = max(v,0)+(exp(min(v,0))-1) (exact for v>0), reduce
//     via float2 ext-vectors -> v_pk_max/min/add/fma_f32 on gfx950.
// Staging: r17's 3-deep ring + loads 2 iters ahead + lgkmcnt-only barriers
// (global loads stay in flight across barriers) kept verbatim.
//
// v_mfma_f32_32x32x16_bf16 mapping (validated r2-r11):
//   A: lane l, reg j -> A[l&31][j + 8*(l>>5)]
//   B: lane l, reg j -> B[j + 8*(l>>5)][l&31]
//   D: lane l, reg r -> row u=(r&3)+8*(r>>2)+4*(l>>5), col b=l&31
// Packed A-frag: lanes<32 = bf16(W1^T) (k<8), lanes>=32 = bf16(W1-hi) (k>=8).
// D = (whi+wlo)*xhi + b1 (C-in fp32). LN+Dense2 folded:
//   out = rsqrt(var+eps)*(dot(e,g2) - mu*G) + C.
// Block = 4 waves = q-tile; 4 iters x 64 rows = 256-row band; grid (64,32).

typedef __attribute__((ext_vector_type(8))) short short8;    // 8 bf16
typedef __attribute__((ext_vector_type(16))) float f32x16;
typedef __attribute__((ext_vector_type(2)))  float f32x2;

#define XS_STRIDE 40   // shorts per staged row (80 B): b128-aligned, 0-conflict

__device__ __forceinline__ short fbits(__bf16 b) { return __builtin_bit_cast(short, b); }

__device__ __forceinline__ short4 cvt4(float4 v) {
    short4 r;
    r.x = fbits((__bf16)v.x); r.y = fbits((__bf16)v.y);
    r.z = fbits((__bf16)v.z); r.w = fbits((__bf16)v.w);
    return r;
}

// barrier WITHOUT vmcnt drain: DS visibility only; global loads stay in flight
__device__ __forceinline__ void barrier_ds_only() {
    asm volatile("s_waitcnt lgkmcnt(0)" ::: "memory");
    __builtin_amdgcn_s_barrier();
}

__global__ __launch_bounds__(256, 4) void divenc_mfma(
    const float* __restrict__ x,      // (16384, 1024)
    const float* __restrict__ W1,     // (128, 8, 32)
    const float* __restrict__ b1,     // (128, 32)
    const float* __restrict__ gamma,  // (128, 32)
    const float* __restrict__ beta,   // (128, 32)
    const float* __restrict__ W2,     // (128, 32)
    const float* __restrict__ b2,     // (128,)
    float* __restrict__ out)          // (16384, 128)
{
    __shared__ short xs[3][64 * XS_STRIDE];   // 3-deep staged panels (15 KB)
    __shared__ float pl[3][2][4][256];        // partials [metric][half][q][row] (24 KB)
    __shared__ float GC[4][2];                // per-q {G, C}

    const int tid  = threadIdx.x;
    const int w    = tid >> 6;
    const int ln   = tid & 63;
    const int u    = ln & 31;
    const int half = ln >> 5;
    const int qt   = blockIdx.y;      // 0..31
    const int q    = qt * 4 + w;
    const int bx   = blockIdx.x;      // 0..63; band = rows bx*256..+255
    const int band = bx * 256;

    // staging role: 8 threads cover one 128B row; thread t does rows t>>3, +32
    const int srow0 = tid >> 3;
    const int srow1 = srow0 + 32;
    const int schk  = tid & 7;
    const float* xpan = x + qt * 32 + schk * 4;

    // ---- A-frag: lanes<32 = whi (k=0..7), lanes>=32 = wlo (k=8..15) ----
    short8 wfrag;
    #pragma unroll
    for (int j = 0; j < 8; ++j) {
        float f  = W1[q * 256 + j * 32 + u];
        __bf16 h = (__bf16)f;
        wfrag[j] = half ? fbits((__bf16)(f - (float)h)) : fbits(h);
    }

    // ---- params: biasr (MFMA C-in) + g2r in regs; G,C -> LDS ----
    f32x16 biasr, g2r;
    {
        float gs = 0.f, cs = 0.f;
        #pragma unroll
        for (int c = 0; c < 4; ++c) {
            const int ub = q * 32 + 4 * half + 8 * c;
            float4 b1v = *(const float4*)&b1[ub];
            float4 gav = *(const float4*)&gamma[ub];
            float4 w2v = *(const float4*)&W2[ub];
            float4 bev = *(const float4*)&beta[ub];
            #pragma unroll
            for (int j = 0; j < 4; ++j) {
                float g2 = ((const float*)&gav)[j] * ((const float*)&w2v)[j];
                biasr[4 * c + j] = ((const float*)&b1v)[j];
                g2r[4 * c + j]   = g2;
                gs += g2;
                cs += ((const float*)&bev)[j] * ((const float*)&w2v)[j];
            }
        }
        gs += __shfl_xor(gs, 32);   // setup-only shuffles
        cs += __shfl_xor(cs, 32);
        if (ln == 0) {
            GC[w][0] = gs;
            GC[w][1] = cs + b2[q];
        }
    }

    // ---- prologue: stage panel 0; issue panel 1's loads (stay in flight) ----
    {
        float4 g0 = *(const float4*)(xpan + (size_t)(band + srow0) * 1024);
        float4 g1 = *(const float4*)(xpan + (size_t)(band + srow1) * 1024);
        *(short4*)&xs[0][srow0 * XS_STRIDE + schk * 4] = cvt4(g0);
        *(short4*)&xs[0][srow1 * XS_STRIDE + schk * 4] = cvt4(g1);
    }
    float4 p0 = *(const float4*)(xpan + (size_t)(band + 64 + srow0) * 1024);
    float4 p1 = *(const float4*)(xpan + (size_t)(band + 64 + srow1) * 1024);
    barrier_ds_only();

    const f32x2 zero2 = {0.f, 0.f};
    const f32x2 one2  = {1.f, 1.f};

    #pragma unroll 1
    for (int it = 0; it < 4; ++it) {
        const int cur = it % 3;
        const int nxt = (it + 1) % 3;
        const int b0  = it * 64;        // row offset within band

        // issue loads for panel it+2 (2 iterations ahead; stay in flight)
        float4 f0, f1;
        if (it < 2) {
            f0 = *(const float4*)(xpan + (size_t)(band + b0 + 128 + srow0) * 1024);
            f1 = *(const float4*)(xpan + (size_t)(band + b0 + 128 + srow1) * 1024);
        }

        // ---- compute on panel cur ----
        short8 xa = *(const short8*)&xs[cur][u * XS_STRIDE + w * 8];
        short8 xb = *(const short8*)&xs[cur][(u + 32) * XS_STRIDE + w * 8];

        f32x16 accA = __builtin_amdgcn_mfma_f32_32x32x16_bf16(wfrag, xa, biasr, 0, 0, 0);
        f32x16 accB = __builtin_amdgcn_mfma_f32_32x32x16_bf16(wfrag, xb, biasr, 0, 0, 0);

        // ---- packed ELU + partial reductions (no shfl, no epilogue) ----
        #pragma unroll
        for (int t = 0; t < 2; ++t) {
            const f32x16& acc = t ? accB : accA;
            f32x2 vs = zero2, vq = zero2, vd = zero2;
            #pragma unroll
            for (int i = 0; i < 8; ++i) {
                f32x2 va = { acc[2 * i], acc[2 * i + 1] };
                f32x2 g2 = { g2r[2 * i], g2r[2 * i + 1] };
                f32x2 mx = __builtin_elementwise_max(va, zero2);   // v_pk_max
                f32x2 mn = __builtin_elementwise_min(va, zero2);   // v_pk_min
                f32x2 ex;
                ex.x = __expf(mn.x);                               // trans pipe
                ex.y = __expf(mn.y);
                f32x2 e = mx + (ex - one2);   // exact v for v>0 (ex-1 == 0)
                vs += e;                       // v_pk_add
                vq += e * e;                   // contract -> v_pk_fma
                vd += e * g2;                  // contract -> v_pk_fma
            }
            const int row = b0 + t * 32 + u;
            pl[0][half][w][row] = vs.x + vs.y;   // conflict-free: row-consecutive
            pl[1][half][w][row] = vq.x + vq.y;
            pl[2][half][w][row] = vd.x + vd.y;
        }

        // ---- write panel it+1 from pending regs (vmcnt counted, not drained) ----
        if (it < 3) {
            *(short4*)&xs[nxt][srow0 * XS_STRIDE + schk * 4] = cvt4(p0);
            *(short4*)&xs[nxt][srow1 * XS_STRIDE + schk * 4] = cvt4(p1);
        }
        barrier_ds_only();

        p0 = f0;
        p1 = f1;
    }

    __syncthreads();   // full drain: all plane writes visible

    // ---- batched gather: thread tid = row tid; 4 epilogues; float4 store ----
    {
        float4 o;
        #pragma unroll
        for (int q4 = 0; q4 < 4; ++q4) {
            float sum = pl[0][0][q4][tid] + pl[0][1][q4][tid];
            float ss  = pl[1][0][q4][tid] + pl[1][1][q4][tid];
            float dot = pl[2][0][q4][tid] + pl[2][1][q4][tid];
            float mu  = sum * 0.03125f;
            float var = fmaf(-mu, mu, ss * 0.03125f);
            float inv = rsqrtf(var + 1e-3f);
            ((float*)&o)[q4] = fmaf(inv, fmaf(-mu, GC[q4][0], dot), GC[q4][1]);
        }
        *(float4*)(out + (size_t)(band + tid) * 128 + qt * 4) = o;
    }
}

extern "C" void kernel_launch(void* const* d_in, const int* in_sizes, int n_in,
                              void* d_out, int out_size, void* d_ws, size_t ws_size,
                              hipStream_t stream) {
    const float* x     = (const float*)d_in[0];
    const float* W1    = (const float*)d_in[1];
    const float* b1    = (const float*)d_in[2];
    const float* gamma = (const float*)d_in[3];
    const float* beta  = (const float*)d_in[4];
    const float* W2    = (const float*)d_in[5];
    const float* b2    = (const float*)d_in[6];
    float* out = (float*)d_out;

    dim3 grid(64, 32);   // (256-row bands, q-tiles of 4) = 2048 blocks
    divenc_mfma<<<grid, 256, 0, stream>>>(x, W1, b1, gamma, beta, W2, b2, out);
}

// Round 20
// 28.055 us; speedup vs baseline: 1.0381x; 1.0317x over previous
//
#include <hip/hip_runtime.h>

// DivEncLayer via MFMA — DEEP PREFETCH: all panels via global_load_lds in the
// prologue, counted vmcnt per iteration (T3/T4). Zero in-loop global loads.
// Per (b,q): h = elu(x[b,q*8:+8]@W1[q] + b1[q]); LN(h); out = h@W2[q]+b2[q].
// B=16384, Q=128, S=8, U=32.
//
// r16-r19 synthesis: phase costs strictly additive (staging 9.8us = memory
// roofline; compute ~15us) -> memory and compute never overlap (convoy).
// Register prefetch can't go deeper than ~1 iter (VGPR). Fix: 4 panels of
// fp32 x staged by 8 global_load_lds dwordx4 per wave (no dest regs), issued
// ALL UPFRONT; iteration k waits s_waitcnt vmcnt(6-2k)+s_barrier only.
// In-order vmcnt retirement makes the counts safe under any compiler
// interleaving of other loads (waits become conservative, never unsafe).
//
// LDS layout: linear [panel][row][32 floats] (gload_lds writes base+lane*16).
// Source-swizzle (m173/m201): lane l stages global chunk (l&7)^(l>>3) so the
// read-side XOR 4*(c^(u&7)) lands on spread banks (4-way max vs 32-way linear).
//
// v_mfma_f32_32x32x16_bf16 mapping (validated r2-r11):
//   A: lane l, reg j -> A[l&31][j+8*(l>>5)]  B: lane l, reg j -> B[j+8*(l>>5)][l&31]
//   D: lane l, reg r -> row u=(r&3)+8*(r>>2)+4*(l>>5), col b=l&31
// Packed A-frag: lanes<32 = bf16(W1^T) (k<8), lanes>=32 = bf16(W1-hi) (k>=8).
// B duplicates rows across halves (both halves read same LDS addr: broadcast).
// D = (whi+wlo)*xhi + b1 (C-in fp32). LN+Dense2 folded:
//   out = rsqrt(var+eps)*(dot(e,g2) - mu*G) + C.
// Block = 4 waves = q-tile; 4 panels x 64 rows = 256-row band; grid (64,32).
// lout gather -> float4 store per row (write-exact, proven).

typedef __attribute__((ext_vector_type(8))) short short8;    // 8 bf16
typedef __attribute__((ext_vector_type(16))) float f32x16;

__device__ __forceinline__ short fbits(__bf16 b) { return __builtin_bit_cast(short, b); }

__device__ __forceinline__ float elu1(float v) {
    return v > 0.f ? v : __expf(v) - 1.f;
}

__device__ __forceinline__ void compute_panel(
    const float* __restrict__ pan, int b0, short8 wfrag,
    const f32x16& biasr, const f32x16& g2r, float G, float C,
    int u, int w, int half, float* __restrict__ lout)
{
    // swizzled read: floats [8w..8w+7] of row r live at slots 4*((2w|2w+1)^(r&7))
    const int s0 = 4 * ((2 * w) ^ (u & 7));
    const int s1 = 4 * ((2 * w + 1) ^ (u & 7));
    float4 a0 = *(const float4*)&pan[u * 32 + s0];           // tile A: row u
    float4 a1 = *(const float4*)&pan[u * 32 + s1];
    float4 c0 = *(const float4*)&pan[1024 + u * 32 + s0];    // tile B: row 32+u
    float4 c1 = *(const float4*)&pan[1024 + u * 32 + s1];

    short8 xa, xb;
    xa[0] = fbits((__bf16)a0.x); xa[1] = fbits((__bf16)a0.y);
    xa[2] = fbits((__bf16)a0.z); xa[3] = fbits((__bf16)a0.w);
    xa[4] = fbits((__bf16)a1.x); xa[5] = fbits((__bf16)a1.y);
    xa[6] = fbits((__bf16)a1.z); xa[7] = fbits((__bf16)a1.w);
    xb[0] = fbits((__bf16)c0.x); xb[1] = fbits((__bf16)c0.y);
    xb[2] = fbits((__bf16)c0.z); xb[3] = fbits((__bf16)c0.w);
    xb[4] = fbits((__bf16)c1.x); xb[5] = fbits((__bf16)c1.y);
    xb[6] = fbits((__bf16)c1.z); xb[7] = fbits((__bf16)c1.w);

    f32x16 accA = __builtin_amdgcn_mfma_f32_32x32x16_bf16(wfrag, xa, biasr, 0, 0, 0);
    f32x16 accB = __builtin_amdgcn_mfma_f32_32x32x16_bf16(wfrag, xb, biasr, 0, 0, 0);

    {
        float sum = 0.f, ss = 0.f, dot = 0.f;
        #pragma unroll
        for (int r = 0; r < 16; ++r) {
            float e = elu1(accA[r]);
            sum += e;
            ss  = fmaf(e, e, ss);
            dot = fmaf(e, g2r[r], dot);
        }
        sum += __shfl_xor(sum, 32);
        ss  += __shfl_xor(ss, 32);
        dot += __shfl_xor(dot, 32);
        float mu  = sum * 0.03125f;
        float var = fmaf(-mu, mu, ss * 0.03125f);
        float inv = rsqrtf(var + 1e-3f);
        float res = fmaf(inv, fmaf(-mu, G, dot), C);
        if (half == 0) lout[(b0 + u) * 5 + w] = res;
    }
    {
        float sum = 0.f, ss = 0.f, dot = 0.f;
        #pragma unroll
        for (int r = 0; r < 16; ++r) {
            float e = elu1(accB[r]);
            sum += e;
            ss  = fmaf(e, e, ss);
            dot = fmaf(e, g2r[r], dot);
        }
        sum += __shfl_xor(sum, 32);
        ss  += __shfl_xor(ss, 32);
        dot += __shfl_xor(dot, 32);
        float mu  = sum * 0.03125f;
        float var = fmaf(-mu, mu, ss * 0.03125f);
        float inv = rsqrtf(var + 1e-3f);
        float res = fmaf(inv, fmaf(-mu, G, dot), C);
        if (half == 0) lout[(b0 + 32 + u) * 5 + w] = res;
    }
}

__global__ __launch_bounds__(256, 4) void divenc_dp(
    const float* __restrict__ x,      // (16384, 1024)
    const float* __restrict__ W1,     // (128, 8, 32)
    const float* __restrict__ b1,     // (128, 32)
    const float* __restrict__ gamma,  // (128, 32)
    const float* __restrict__ beta,   // (128, 32)
    const float* __restrict__ W2,     // (128, 32)
    const float* __restrict__ b2,     // (128,)
    float* __restrict__ out)          // (16384, 128)
{
    __shared__ float xp[4][64 * 32];  // 4 fp32 panels, source-swizzled (32 KB)
    __shared__ float lout[256 * 5];   // results, padded stride 5 (5 KB)

    const int tid  = threadIdx.x;
    const int w    = tid >> 6;
    const int ln   = tid & 63;
    const int u    = ln & 31;
    const int half = ln >> 5;
    const int qt   = blockIdx.y;      // 0..31
    const int q    = qt * 4 + w;
    const int bx   = blockIdx.x;      // 0..63; band = rows bx*256..+255
    const int band = bx * 256;

    // ---- A-frag: lanes<32 = whi (k=0..7), lanes>=32 = wlo (k=8..15) ----
    short8 wfrag;
    #pragma unroll
    for (int j = 0; j < 8; ++j) {
        float f  = W1[q * 256 + j * 32 + u];
        __bf16 h = (__bf16)f;
        wfrag[j] = half ? fbits((__bf16)(f - (float)h)) : fbits(h);
    }

    // ---- params: biasr (MFMA C-in) + g2r in regs, vector loads ----
    f32x16 biasr, g2r;
    float G, C;
    {
        float gs = 0.f, cs = 0.f;
        #pragma unroll
        for (int c = 0; c < 4; ++c) {
            const int ub = q * 32 + 4 * half + 8 * c;
            float4 b1v = *(const float4*)&b1[ub];
            float4 gav = *(const float4*)&gamma[ub];
            float4 w2v = *(const float4*)&W2[ub];
            float4 bev = *(const float4*)&beta[ub];
            #pragma unroll
            for (int j = 0; j < 4; ++j) {
                float g2 = ((const float*)&gav)[j] * ((const float*)&w2v)[j];
                biasr[4 * c + j] = ((const float*)&b1v)[j];
                g2r[4 * c + j]   = g2;
                gs += g2;
                cs += ((const float*)&bev)[j] * ((const float*)&w2v)[j];
            }
        }
        gs += __shfl_xor(gs, 32);   // halves hold complementary u-sets
        cs += __shfl_xor(cs, 32);
        G = gs;
        C = cs + b2[q];
    }

    // ---- prologue: issue ALL 4 panels' loads (8 global_load_lds / wave) ----
    // wave w stages rows w*16..w*16+15 of each panel (2 instrs x 8 rows).
    // lane l -> row (l>>3), slot (l&7); source chunk = (l&7)^(l>>3) (swizzle).
    {
        const int rsub = ln >> 3;                 // 0..7
        const int chk  = (ln & 7) ^ rsub;         // swizzled source 16B chunk
        const float* gsrc = x + qt * 32 + chk * 4;
        #pragma unroll
        for (int p = 0; p < 4; ++p) {
            #pragma unroll
            for (int i = 0; i < 2; ++i) {
                const float* ga = gsrc + (size_t)(band + p * 64 + w * 16 + i * 8 + rsub) * 1024;
                float* la = &xp[p][(w * 16 + i * 8) * 32];   // wave-uniform base
                __builtin_amdgcn_global_load_lds(ga, la, 16, 0, 0);
            }
        }
    }

    // ---- 4 iterations, counted waits: panel p needs own instrs 2p,2p+1 ----
    asm volatile("s_waitcnt vmcnt(6)\n\ts_barrier" ::: "memory");
    compute_panel(&xp[0][0],   0, wfrag, biasr, g2r, G, C, u, w, half, lout);
    asm volatile("s_waitcnt vmcnt(4)\n\ts_barrier" ::: "memory");
    compute_panel(&xp[1][0],  64, wfrag, biasr, g2r, G, C, u, w, half, lout);
    asm volatile("s_waitcnt vmcnt(2)\n\ts_barrier" ::: "memory");
    compute_panel(&xp[2][0], 128, wfrag, biasr, g2r, G, C, u, w, half, lout);
    asm volatile("s_waitcnt vmcnt(0)\n\ts_barrier" ::: "memory");
    compute_panel(&xp[3][0], 192, wfrag, biasr, g2r, G, C, u, w, half, lout);

    __syncthreads();   // lout visibility for the gather

    // ---- gather/store: 256 rows, one float4 per thread (write-exact) ----
    {
        float4 o;
        o.x = lout[tid * 5 + 0];
        o.y = lout[tid * 5 + 1];
        o.z = lout[tid * 5 + 2];
        o.w = lout[tid * 5 + 3];
        *(float4*)(out + (size_t)(band + tid) * 128 + qt * 4) = o;
    }
}

extern "C" void kernel_launch(void* const* d_in, const int* in_sizes, int n_in,
                              void* d_out, int out_size, void* d_ws, size_t ws_size,
                              hipStream_t stream) {
    const float* x     = (const float*)d_in[0];
    const float* W1    = (const float*)d_in[1];
    const float* b1    = (const float*)d_in[2];
    const float* gamma = (const float*)d_in[3];
    const float* beta  = (const float*)d_in[4];
    const float* W2    = (const float*)d_in[5];
    const float* b2    = (const float*)d_in[6];
    float* out = (float*)d_out;

    dim3 grid(64, 32);   // (256-row bands, q-tiles of 4) = 2048 blocks
    divenc_dp<<<grid, 256, 0, stream>>>(x, W1, b1, gamma, beta, W2, b2, out);
}